// Round 8
// baseline (1104.440 us; speedup 1.0000x reference)
//
#include <hip/hip_runtime.h>
#include <math.h>

constexpr int BATCH = 4;
constexpr int SEQ   = 2048;
constexpr int HID   = 2048;
constexpr int NHEAD = 8;
constexpr int HD    = 256;
constexpr int QKVN  = (NHEAD + 2) * HD;          // 2560
constexpr float SCL = 0.0625f;                   // 256^-0.5

typedef __bf16 bf16_t;
typedef __bf16 bf16x8 __attribute__((ext_vector_type(8)));
typedef float  f32x4  __attribute__((ext_vector_type(4)));

__device__ __forceinline__ f32x4 zero4() {
  f32x4 z; z[0] = 0.f; z[1] = 0.f; z[2] = 0.f; z[3] = 0.f; return z;
}

__device__ __forceinline__ f32x4 mfma16(bf16x8 a, bf16x8 b, f32x4 c) {
  return __builtin_amdgcn_mfma_f32_16x16x32_bf16(a, b, c, 0, 0, 0);
}

// async global->LDS, 16B per lane. lds must be wave-uniform base; HW adds lane*16.
__device__ __forceinline__ void gl2lds16(const void* g, void* lds) {
  typedef __attribute__((address_space(1))) void* gp_t;
  typedef __attribute__((address_space(3))) void* lp_t;
  __builtin_amdgcn_global_load_lds((gp_t)(size_t)g,
                                   (lp_t)(unsigned int)(size_t)lds, 16, 0, 0);
}

__device__ __forceinline__ float rmax16(float v) {
#pragma unroll
  for (int o = 1; o < 16; o <<= 1) v = fmaxf(v, __shfl_xor(v, o));
  return v;
}
__device__ __forceinline__ float rsum16(float v) {
#pragma unroll
  for (int o = 1; o < 16; o <<= 1) v += __shfl_xor(v, o);
  return v;
}

// ---------- fp32 -> bf16 bulk convert (8 elems/thread) ----------
__global__ __launch_bounds__(256)
void cvt_bf16_kernel(const float* __restrict__ in, bf16_t* __restrict__ out) {
  const int i = blockIdx.x * 256 + threadIdx.x;
  const float4 a = ((const float4*)in)[i * 2];
  const float4 b = ((const float4*)in)[i * 2 + 1];
  bf16x8 o;
  o[0] = (bf16_t)a.x; o[1] = (bf16_t)a.y; o[2] = (bf16_t)a.z; o[3] = (bf16_t)a.w;
  o[4] = (bf16_t)b.x; o[5] = (bf16_t)b.y; o[6] = (bf16_t)b.z; o[7] = (bf16_t)b.w;
  ((bf16x8*)out)[i] = o;
}

// ---------- w[K][N] fp32 -> wT[N][K] bf16, 64x64 tiles ----------
__global__ __launch_bounds__(256)
void transw_kernel(const float* __restrict__ w, bf16_t* __restrict__ wT, int K, int N) {
  __shared__ __align__(16) bf16_t tile[64][72];
  const int n0 = blockIdx.x * 64, k0 = blockIdx.y * 64;
  const int t = threadIdx.x, rr = t >> 3, c8 = (t & 7) * 8;
#pragma unroll
  for (int it = 0; it < 2; ++it) {
    const int r = rr + it * 32;
    const float4* p = (const float4*)(w + (size_t)(k0 + r) * N + n0 + c8);
    const float4 a = p[0], b = p[1];
    bf16x8 o;
    o[0] = (bf16_t)a.x; o[1] = (bf16_t)a.y; o[2] = (bf16_t)a.z; o[3] = (bf16_t)a.w;
    o[4] = (bf16_t)b.x; o[5] = (bf16_t)b.y; o[6] = (bf16_t)b.z; o[7] = (bf16_t)b.w;
    *(bf16x8*)&tile[r][c8] = o;
  }
  __syncthreads();
#pragma unroll
  for (int it = 0; it < 2; ++it) {
    const int rn = rr + it * 32;
    bf16x8 o;
#pragma unroll
    for (int j = 0; j < 8; ++j) o[j] = tile[c8 + j][rn];
    *(bf16x8*)&wT[(size_t)(n0 + rn) * K + k0 + c8] = o;
  }
}

// =====================================================================
// 256x256 8-phase GEMM (m201 template, plain HIP): C[M][N] = A * BT^T
// (verified round 3: correct, both dispatches < 139 us)
// =====================================================================
#define BAR()   __builtin_amdgcn_s_barrier()
#define LGKM0() do { asm volatile("s_waitcnt lgkmcnt(0)" ::: "memory"); \
                     __builtin_amdgcn_sched_barrier(0); } while (0)
#define VMC(n)  asm volatile("s_waitcnt vmcnt(" #n ")" ::: "memory")

template <typename TC>
__global__ __launch_bounds__(512)
void gemm256_kernel(const bf16_t* __restrict__ A, const bf16_t* __restrict__ BT,
                    TC* __restrict__ C, int M, int N, int K) {
  __shared__ __align__(16) bf16_t As[2][2][128 * 64];   // [buf][half] 64 KB
  __shared__ __align__(16) bf16_t Bs[2][2][128 * 64];   // 64 KB

  const int tid = threadIdx.x;
  const int w = tid >> 6, lane = tid & 63;
  const int wr = w >> 2, wc = w & 3;
  const int quad = lane >> 4, l15 = lane & 15;
  const int bm = blockIdx.y * 256, bn = blockIdx.x * 256;

  const int srow = tid >> 3;                    // 0..63 row within 64-row chunk
  const int sc16 = (tid & 7) ^ (srow & 7);      // pre-swizzled source chunk
  const bf16_t* Asrc = A  + (size_t)(bm + srow) * K + sc16 * 8;
  const bf16_t* Bsrc = BT + (size_t)(bn + srow) * K + sc16 * 8;

#define STAGE_A(t, h) do {                                                  \
    const bf16_t* _s = Asrc + (size_t)((h) * 128) * K + (t) * 64;           \
    gl2lds16(_s,                 &As[(t) & 1][h][w * 512]);                 \
    gl2lds16(_s + (size_t)64 * K, &As[(t) & 1][h][4096 + w * 512]);         \
  } while (0)
#define STAGE_B(t, h) do {                                                  \
    const bf16_t* _s = Bsrc + (size_t)((h) * 128) * K + (t) * 64;           \
    gl2lds16(_s,                 &Bs[(t) & 1][h][w * 512]);                 \
    gl2lds16(_s + (size_t)64 * K, &Bs[(t) & 1][h][4096 + w * 512]);         \
  } while (0)

  const int c0  = ((quad ^ (l15 & 7)) << 3);
  const int aro = l15 * 64;                     // + mt*1024
  const int bh  = wc >> 1;
  const int bro = ((wc & 1) * 64 + l15) * 64;   // + nt*1024

  f32x4 acc[8][4];
#pragma unroll
  for (int mt = 0; mt < 8; ++mt)
#pragma unroll
    for (int nt = 0; nt < 4; ++nt) acc[mt][nt] = zero4();

  bf16x8 bfr[4][2], a01[2][2], a2[6][2];

#define LD_B(b) do { _Pragma("unroll")                                      \
    for (int nt = 0; nt < 4; ++nt) {                                        \
      bfr[nt][0] = *(const bf16x8*)&Bs[b][bh][bro + nt * 1024 + c0];        \
      bfr[nt][1] = *(const bf16x8*)&Bs[b][bh][bro + nt * 1024 + (c0 ^ 32)]; \
    } } while (0)
#define LD_A01(b) do { _Pragma("unroll")                                    \
    for (int mt = 0; mt < 2; ++mt) {                                        \
      a01[mt][0] = *(const bf16x8*)&As[b][wr][aro + mt * 1024 + c0];        \
      a01[mt][1] = *(const bf16x8*)&As[b][wr][aro + mt * 1024 + (c0 ^ 32)]; \
    } } while (0)
#define LD_A2(b) do { _Pragma("unroll")                                     \
    for (int i = 0; i < 6; ++i) {                                           \
      a2[i][0] = *(const bf16x8*)&As[b][wr][aro + (i + 2) * 1024 + c0];     \
      a2[i][1] = *(const bf16x8*)&As[b][wr][aro + (i + 2) * 1024 + (c0^32)];\
    } } while (0)
#define MFMA8(A0, A1, mb) do {                                              \
    __builtin_amdgcn_s_setprio(1);                                          \
    _Pragma("unroll")                                                       \
    for (int nt = 0; nt < 4; ++nt) {                                        \
      acc[(mb)][nt]     = mfma16((A0)[0], bfr[nt][0], acc[(mb)][nt]);       \
      acc[(mb)][nt]     = mfma16((A0)[1], bfr[nt][1], acc[(mb)][nt]);       \
      acc[(mb)+1][nt]   = mfma16((A1)[0], bfr[nt][0], acc[(mb)+1][nt]);     \
      acc[(mb)+1][nt]   = mfma16((A1)[1], bfr[nt][1], acc[(mb)+1][nt]);     \
    }                                                                       \
    __builtin_amdgcn_s_setprio(0);                                          \
  } while (0)

  const int NITER = K >> 7;                     // K/128 (two BK=64 tiles/iter)

  STAGE_A(0, 0); STAGE_A(0, 1); STAGE_B(0, 0); STAGE_B(0, 1);
  STAGE_A(1, 0); STAGE_A(1, 1);
  VMC(4);
  BAR();

  for (int u = 0; u < NITER; ++u) {
    const bool last = (u == NITER - 1);
    const int t1 = 2 * u + 1, t2 = 2 * u + 2, t3 = 2 * u + 3;

    LD_B(0); LD_A01(0);
    STAGE_B(t1, 0);
    BAR(); LGKM0();
    MFMA8(a01[0], a01[1], 0);
    BAR();
    LD_A2(0);
    STAGE_B(t1, 1);
    BAR(); LGKM0();
    MFMA8(a2[0], a2[1], 2);
    BAR();
    if (!last) STAGE_A(t2, 0);
    BAR();
    MFMA8(a2[2], a2[3], 4);
    BAR();
    if (!last) { STAGE_A(t2, 1); VMC(4); } else { VMC(0); }
    BAR();
    MFMA8(a2[4], a2[5], 6);
    BAR();
    LD_B(1); LD_A01(1);
    if (!last) STAGE_B(t2, 0);
    BAR(); LGKM0();
    MFMA8(a01[0], a01[1], 0);
    BAR();
    LD_A2(1);
    if (!last) STAGE_B(t2, 1);
    BAR(); LGKM0();
    MFMA8(a2[0], a2[1], 2);
    BAR();
    if (!last) STAGE_A(t3, 0);
    BAR();
    MFMA8(a2[2], a2[3], 4);
    BAR();
    if (!last) { STAGE_A(t3, 1); VMC(4); }
    BAR();
    MFMA8(a2[4], a2[5], 6);
    BAR();
  }

#pragma unroll
  for (int mt = 0; mt < 8; ++mt)
#pragma unroll
    for (int nt = 0; nt < 4; ++nt)
#pragma unroll
      for (int r = 0; r < 4; ++r) {
        const int row = bm + wr * 128 + mt * 16 + quad * 4 + r;
        const int col = bn + wc * 64 + nt * 16 + l15;
        C[(size_t)row * N + col] = (TC)acc[mt][nt][r];
      }
#undef STAGE_A
#undef STAGE_B
#undef LD_B
#undef LD_A01
#undef LD_A2
#undef MFMA8
}

// ---------- RoPE cos/sin table: tab[s][i] = (cos, sin) ----------
__global__ __launch_bounds__(128)
void rope_table_kernel(const int* __restrict__ pos, float2* __restrict__ tab) {
  const int s = blockIdx.x, i = threadIdx.x;
  const float inv_freq = powf(10000.0f, -(float)i / 128.0f);
  const float ang = (float)pos[s] * inv_freq;
  float sn, cs;
  sincosf(ang, &sn, &cs);
  tab[s * 128 + i] = make_float2(cs, sn);
}

// ---------- RoPE apply, table-driven, bf16x8 vectorized ----------
__global__ __launch_bounds__(256)
void rope_kernel(const float2* __restrict__ tab, bf16_t* __restrict__ qkv) {
  const int bs = blockIdx.x * 16 + (threadIdx.x >> 4);
  const int h  = blockIdx.y;
  const int i0 = (threadIdx.x & 15) * 8;
  const int s  = bs & (SEQ - 1);
  const size_t base = (size_t)bs * QKVN + (size_t)h * HD;
  bf16x8 a = *(const bf16x8*)&qkv[base + i0];
  bf16x8 b = *(const bf16x8*)&qkv[base + 128 + i0];
  bf16x8 oa, ob;
#pragma unroll
  for (int j = 0; j < 8; ++j) {
    const float2 t = tab[s * 128 + i0 + j];
    const float x1 = (float)a[j], x2 = (float)b[j];
    oa[j] = (bf16_t)(x1 * t.x - x2 * t.y);
    ob[j] = (bf16_t)(x2 * t.x + x1 * t.y);
  }
  *(bf16x8*)&qkv[base + i0]       = oa;
  *(bf16x8*)&qkv[base + 128 + i0] = ob;
}

// ---------- V transpose: qkv v-part [s][d] -> Vt[b][d][s] ----------
__global__ __launch_bounds__(256)
void vtrans_kernel(const bf16_t* __restrict__ qkv, bf16_t* __restrict__ Vt) {
  __shared__ __align__(16) bf16_t tile[64][72];
  const int s0 = blockIdx.x * 64, d0 = blockIdx.y * 64, b = blockIdx.z;
  const int t = threadIdx.x, rr = t >> 3, c8 = (t & 7) * 8;
#pragma unroll
  for (int it = 0; it < 2; ++it) {
    const int r = rr + it * 32;
    *(bf16x8*)&tile[r][c8] =
        *(const bf16x8*)&qkv[(size_t)(b * SEQ + s0 + r) * QKVN + 2304 + d0 + c8];
  }
  __syncthreads();
#pragma unroll
  for (int it = 0; it < 2; ++it) {
    const int dd = rr + it * 32;
    bf16x8 o;
#pragma unroll
    for (int j = 0; j < 8; ++j) o[j] = tile[c8 + j][dd];
    *(bf16x8*)&Vt[(size_t)(b * HD + d0 + dd) * SEQ + s0 + c8] = o;
  }
}

// ---------- flash attention: 1024 thr = 16 waves, 1 block/CU, grid 256 ------
// 16 waves/CU achieved INSIDE one block: no co-scheduling or dispatch-order
// assumptions (R4/R5/R7 all failed on those). Waves = 8 heads x 2 q-tiles.
// Per phase p, block j runs the q-tile pair (base, base+1), base = p ? 126-2j
// : 2j (even) -> ntiles(base) == ntiles(base+1) exactly, so no idle waves;
// phase-sum uniform ~33 tiles for every block. K/V staged once per tile and
// shared by 16 waves. P (16 x 2 KB = 32 KB) aliases the whole Ks buffer
// (R6-verified: extra barrier between QK^T and P-write). LDS = 64 KB.
// VGPR ~116 (per-wave code unchanged) -> 4 waves/SIMD fits. Plain
// __launch_bounds__(1024): NEVER pass the min-occupancy arg (R6: VGPR=64,
// total spill).
__global__ __launch_bounds__(1024)
void attn_kernel(const bf16_t* __restrict__ qkv, const bf16_t* __restrict__ Vt,
                 bf16_t* __restrict__ O) {
  __shared__ __align__(16) bf16_t Ks[64 * 256];     // [key][d]; whole buf re-used as P
  __shared__ __align__(16) bf16_t Vts[256 * 64];    // [d][key], chunk-swizzled

  const int tid = threadIdx.x, w = tid >> 6, lane = tid & 63;
  const int quad = lane >> 4, l15 = lane & 15;
  const int b = blockIdx.x >> 6;
  const int j = blockIdx.x & 63;
  const int h = w & 7;                               // head
  const int g = w >> 3;                              // q-tile within pair

  bf16_t* PKs = &Ks[w * 1024];                       // per-wave 16x64 P region

  const bf16_t* kbase0 = qkv + (size_t)(b * SEQ) * QKVN + 2048;
  const bf16_t* vbase0 = Vt + (size_t)b * HD * SEQ;

  for (int p = 0; p < 2; ++p) {
    const int base = p ? (126 - 2 * j) : (2 * j);    // even
    const int qt = base + g;
    const int q0 = qt * 16;
    const int ntiles = base / 4 + 1;                 // same for g=0 and g=1

    // Q fragments (A-layout: m = l15, k = quad*8+jj)
    bf16x8 qf[8];
    const bf16_t* qp =
        qkv + (size_t)(b * SEQ + q0 + l15) * QKVN + (size_t)h * HD + quad * 8;
#pragma unroll
    for (int ks = 0; ks < 8; ++ks) qf[ks] = *(const bf16x8*)(qp + ks * 32);

    float mrun[4], lrun[4];
    f32x4 of[16];
#pragma unroll
    for (int r = 0; r < 4; ++r) { mrun[r] = -3e38f; lrun[r] = 0.f; }
#pragma unroll
    for (int dt = 0; dt < 16; ++dt) of[dt] = zero4();

    for (int kt = 0; kt < ntiles; ++kt) {
      // ---- stage K (64x256) + Vt (256x64): 1024 threads, 2 chunks each ----
      const bf16_t* kbase = kbase0 + (size_t)(kt * 64) * QKVN;
      const bf16_t* vbase = vbase0 + kt * 64;
#pragma unroll
      for (int i = 0; i < 2; ++i) {
        const int c = i * 1024 + tid;
        const int kr = c >> 5, kc = c & 31;          // K: 32 chunks per 256-d row
        gl2lds16(kbase + (size_t)kr * QKVN + ((kc ^ (kr & 31)) << 3),
                 &Ks[(i * 1024 + w * 64) * 8]);
        const int vr = c >> 3, vc = c & 7;           // V: 8 chunks per 64-key row
        gl2lds16(vbase + (size_t)vr * SEQ + ((vc ^ (vr & 7)) << 3),
                 &Vts[(i * 1024 + w * 64) * 8]);
      }
      __syncthreads();

      // ---- S = Q K^T ----
      f32x4 sf[4];
#pragma unroll
      for (int nt = 0; nt < 4; ++nt) {
        f32x4 acc = zero4();
        const int row = nt * 16 + l15;
#pragma unroll
        for (int ks = 0; ks < 8; ++ks) {
          const int jj = ks * 4 + quad;
          const bf16x8 kf = *(const bf16x8*)&Ks[row * 256 + ((jj ^ (row & 31)) << 3)];
          acc = mfma16(qf[ks], kf, acc);
        }
        sf[nt] = acc;
      }

      // ---- scale + (diagonal-tile-only) causal mask + row max (reg-only) ----
      const bool lastTile = (kt == ntiles - 1);
      float mx[4];
#pragma unroll
      for (int r = 0; r < 4; ++r) {
        const int qg = q0 + quad * 4 + r;
        float v = -3e38f;
#pragma unroll
        for (int nt = 0; nt < 4; ++nt) {
          float s = sf[nt][r] * SCL;
          if (lastTile) {
            const int kg = kt * 64 + nt * 16 + l15;
            if (kg > qg) s = -3e38f;
          }
          sf[nt][r] = s;
          v = fmaxf(v, s);
        }
        mx[r] = rmax16(v);
      }

      // ---- defer-max (T13) ----
      float gg = 0.f;
#pragma unroll
      for (int r = 0; r < 4; ++r) gg = fmaxf(gg, mx[r] - mrun[r]);
      const bool resc = !__all(gg <= 8.0f);
      f32x4 av;
      if (resc) {
#pragma unroll
        for (int r = 0; r < 4; ++r) {
          const float mn = fmaxf(mrun[r], mx[r]);
          av[r] = __expf(mrun[r] - mn);
          mrun[r] = mn;
          lrun[r] *= av[r];
        }
      }

      __syncthreads();   // ALL waves done reading Ks before P overwrites it

      // ---- P = exp(S - m) into XOR-swizzled P (aliasing Ks), row sums ----
#pragma unroll
      for (int r = 0; r < 4; ++r) {
        const int rowp = quad * 4 + r;
        float sum = 0.f;
#pragma unroll
        for (int nt = 0; nt < 4; ++nt) {
          const float pv = __expf(sf[nt][r] - mrun[r]);
          PKs[rowp * 64 + ((((nt * 2 + (l15 >> 3)) ^ (rowp & 7)) << 3) + (l15 & 7))] =
              (bf16_t)pv;
          sum += pv;
        }
        lrun[r] += rsum16(sum);
      }
      if (resc) {
#pragma unroll
        for (int dt = 0; dt < 16; ++dt) of[dt] *= av;
      }
      __asm__ volatile("s_waitcnt lgkmcnt(0)" ::: "memory");  // wave-local P handoff

      // ---- O += P V ----
      bf16x8 pa[2];
#pragma unroll
      for (int k2 = 0; k2 < 2; ++k2)
        pa[k2] = *(const bf16x8*)&PKs[l15 * 64 + (((k2 * 4 + quad) ^ (l15 & 7)) << 3)];
#pragma unroll
      for (int dt = 0; dt < 16; ++dt) {
        const int row = dt * 16 + l15;
#pragma unroll
        for (int k2 = 0; k2 < 2; ++k2) {
          const int jj = k2 * 4 + quad;
          const bf16x8 vf = *(const bf16x8*)&Vts[row * 64 + ((jj ^ (row & 7)) << 3)];
          of[dt] = mfma16(pa[k2], vf, of[dt]);
        }
      }

      __syncthreads();   // all reads of P(Ks)/Vts done before next stage overwrites
    }

    // ---- epilogue: O /= l, store bf16 [b][s][h*HD+d] ----
    f32x4 iv;
#pragma unroll
    for (int r = 0; r < 4; ++r) iv[r] = 1.0f / lrun[r];
#pragma unroll
    for (int dt = 0; dt < 16; ++dt) {
      const f32x4 o = of[dt] * iv;
#pragma unroll
      for (int r = 0; r < 4; ++r)
        O[(size_t)(b * SEQ + q0 + quad * 4 + r) * HID + (size_t)h * HD + dt * 16 + l15] =
            (bf16_t)o[r];
    }
  }
}

// ---------- launch ----------
extern "C" void kernel_launch(void* const* d_in, const int* in_sizes, int n_in,
                              void* d_out, int out_size, void* d_ws, size_t ws_size,
                              hipStream_t stream) {
  const float* hidden  = (const float*)d_in[0];
  const int* positions = (const int*)d_in[1];
  const float* w_qkv   = (const float*)d_in[2];
  const float* w_o     = (const float*)d_in[3];
  float* out           = (float*)d_out;

  char* ws = (char*)d_ws;
  bf16_t* hiddenB = (bf16_t*)ws; ws += (size_t)8192 * 2048 * 2;   // 33.5 MB
  bf16_t* wqkvT   = (bf16_t*)ws; ws += (size_t)2560 * 2048 * 2;   // 10.5 MB
  bf16_t* woT     = (bf16_t*)ws; ws += (size_t)2048 * 2048 * 2;   //  8.4 MB
  bf16_t* qkvB    = (bf16_t*)ws; ws += (size_t)8192 * 2560 * 2;   // 41.9 MB
  bf16_t* VtB     = (bf16_t*)ws; ws += (size_t)4 * 256 * 2048 * 2;//  4.2 MB
  bf16_t* attnB   = (bf16_t*)ws;                                  // 33.5 MB

  // rope table aliases the attnB region (2 MB << 33.5 MB); consumed before
  // attn_kernel writes attnB.
  float2* ropeTab = (float2*)attnB;

  cvt_bf16_kernel<<<8192, 256, 0, stream>>>(hidden, hiddenB);
  transw_kernel<<<dim3(QKVN / 64, HID / 64), 256, 0, stream>>>(w_qkv, wqkvT, HID, QKVN);
  transw_kernel<<<dim3(HID / 64, HID / 64), 256, 0, stream>>>(w_o, woT, HID, HID);
  rope_table_kernel<<<SEQ, 128, 0, stream>>>(positions, ropeTab);

  gemm256_kernel<bf16_t><<<dim3(QKVN / 256, 8192 / 256), 512, 0, stream>>>
      (hiddenB, wqkvT, qkvB, 8192, QKVN, HID);

  rope_kernel<<<dim3(BATCH * SEQ / 16, 9), 256, 0, stream>>>(ropeTab, qkvB);
  vtrans_kernel<<<dim3(SEQ / 64, HD / 64, BATCH), 256, 0, stream>>>(qkvB, VtB);

  attn_kernel<<<256, 1024, 0, stream>>>(qkvB, VtB, attnB);

  gemm256_kernel<float><<<dim3(HID / 256, 8192 / 256), 512, 0, stream>>>
      (attnB, woT, out, 8192, HID, HID);
}

// Round 9
// 483.676 us; speedup vs baseline: 2.2834x; 2.2834x over previous
//
#include <hip/hip_runtime.h>
#include <math.h>

constexpr int BATCH = 4;
constexpr int SEQ   = 2048;
constexpr int HID   = 2048;
constexpr int NHEAD = 8;
constexpr int HD    = 256;
constexpr int QKVN  = (NHEAD + 2) * HD;          // 2560
constexpr float SCL = 0.0625f;                   // 256^-0.5

typedef __bf16 bf16_t;
typedef __bf16 bf16x8 __attribute__((ext_vector_type(8)));
typedef float  f32x4  __attribute__((ext_vector_type(4)));

__device__ __forceinline__ f32x4 zero4() {
  f32x4 z; z[0] = 0.f; z[1] = 0.f; z[2] = 0.f; z[3] = 0.f; return z;
}

__device__ __forceinline__ f32x4 mfma16(bf16x8 a, bf16x8 b, f32x4 c) {
  return __builtin_amdgcn_mfma_f32_16x16x32_bf16(a, b, c, 0, 0, 0);
}

// async global->LDS, 16B per lane. lds must be wave-uniform base; HW adds lane*16.
__device__ __forceinline__ void gl2lds16(const void* g, void* lds) {
  typedef __attribute__((address_space(1))) void* gp_t;
  typedef __attribute__((address_space(3))) void* lp_t;
  __builtin_amdgcn_global_load_lds((gp_t)(size_t)g,
                                   (lp_t)(unsigned int)(size_t)lds, 16, 0, 0);
}

__device__ __forceinline__ float rmax16(float v) {
#pragma unroll
  for (int o = 1; o < 16; o <<= 1) v = fmaxf(v, __shfl_xor(v, o));
  return v;
}
__device__ __forceinline__ float rsum16(float v) {
#pragma unroll
  for (int o = 1; o < 16; o <<= 1) v += __shfl_xor(v, o);
  return v;
}

// ---------- fp32 -> bf16 bulk convert (8 elems/thread) ----------
__global__ __launch_bounds__(256)
void cvt_bf16_kernel(const float* __restrict__ in, bf16_t* __restrict__ out) {
  const int i = blockIdx.x * 256 + threadIdx.x;
  const float4 a = ((const float4*)in)[i * 2];
  const float4 b = ((const float4*)in)[i * 2 + 1];
  bf16x8 o;
  o[0] = (bf16_t)a.x; o[1] = (bf16_t)a.y; o[2] = (bf16_t)a.z; o[3] = (bf16_t)a.w;
  o[4] = (bf16_t)b.x; o[5] = (bf16_t)b.y; o[6] = (bf16_t)b.z; o[7] = (bf16_t)b.w;
  ((bf16x8*)out)[i] = o;
}

// ---------- w[K][N] fp32 -> wT[N][K] bf16, 64x64 tiles ----------
__global__ __launch_bounds__(256)
void transw_kernel(const float* __restrict__ w, bf16_t* __restrict__ wT, int K, int N) {
  __shared__ __align__(16) bf16_t tile[64][72];
  const int n0 = blockIdx.x * 64, k0 = blockIdx.y * 64;
  const int t = threadIdx.x, rr = t >> 3, c8 = (t & 7) * 8;
#pragma unroll
  for (int it = 0; it < 2; ++it) {
    const int r = rr + it * 32;
    const float4* p = (const float4*)(w + (size_t)(k0 + r) * N + n0 + c8);
    const float4 a = p[0], b = p[1];
    bf16x8 o;
    o[0] = (bf16_t)a.x; o[1] = (bf16_t)a.y; o[2] = (bf16_t)a.z; o[3] = (bf16_t)a.w;
    o[4] = (bf16_t)b.x; o[5] = (bf16_t)b.y; o[6] = (bf16_t)b.z; o[7] = (bf16_t)b.w;
    *(bf16x8*)&tile[r][c8] = o;
  }
  __syncthreads();
#pragma unroll
  for (int it = 0; it < 2; ++it) {
    const int rn = rr + it * 32;
    bf16x8 o;
#pragma unroll
    for (int j = 0; j < 8; ++j) o[j] = tile[c8 + j][rn];
    *(bf16x8*)&wT[(size_t)(n0 + rn) * K + k0 + c8] = o;
  }
}

// =====================================================================
// 256x256 8-phase GEMM (m201 template, plain HIP): C[M][N] = A * BT^T
// (verified round 3: correct, both dispatches < 139 us)
// =====================================================================
#define BAR()   __builtin_amdgcn_s_barrier()
#define LGKM0() do { asm volatile("s_waitcnt lgkmcnt(0)" ::: "memory"); \
                     __builtin_amdgcn_sched_barrier(0); } while (0)
#define VMC(n)  asm volatile("s_waitcnt vmcnt(" #n ")" ::: "memory")

template <typename TC>
__global__ __launch_bounds__(512)
void gemm256_kernel(const bf16_t* __restrict__ A, const bf16_t* __restrict__ BT,
                    TC* __restrict__ C, int M, int N, int K) {
  __shared__ __align__(16) bf16_t As[2][2][128 * 64];   // [buf][half] 64 KB
  __shared__ __align__(16) bf16_t Bs[2][2][128 * 64];   // 64 KB

  const int tid = threadIdx.x;
  const int w = tid >> 6, lane = tid & 63;
  const int wr = w >> 2, wc = w & 3;
  const int quad = lane >> 4, l15 = lane & 15;
  const int bm = blockIdx.y * 256, bn = blockIdx.x * 256;

  const int srow = tid >> 3;                    // 0..63 row within 64-row chunk
  const int sc16 = (tid & 7) ^ (srow & 7);      // pre-swizzled source chunk
  const bf16_t* Asrc = A  + (size_t)(bm + srow) * K + sc16 * 8;
  const bf16_t* Bsrc = BT + (size_t)(bn + srow) * K + sc16 * 8;

#define STAGE_A(t, h) do {                                                  \
    const bf16_t* _s = Asrc + (size_t)((h) * 128) * K + (t) * 64;           \
    gl2lds16(_s,                 &As[(t) & 1][h][w * 512]);                 \
    gl2lds16(_s + (size_t)64 * K, &As[(t) & 1][h][4096 + w * 512]);         \
  } while (0)
#define STAGE_B(t, h) do {                                                  \
    const bf16_t* _s = Bsrc + (size_t)((h) * 128) * K + (t) * 64;           \
    gl2lds16(_s,                 &Bs[(t) & 1][h][w * 512]);                 \
    gl2lds16(_s + (size_t)64 * K, &Bs[(t) & 1][h][4096 + w * 512]);         \
  } while (0)

  const int c0  = ((quad ^ (l15 & 7)) << 3);
  const int aro = l15 * 64;                     // + mt*1024
  const int bh  = wc >> 1;
  const int bro = ((wc & 1) * 64 + l15) * 64;   // + nt*1024

  f32x4 acc[8][4];
#pragma unroll
  for (int mt = 0; mt < 8; ++mt)
#pragma unroll
    for (int nt = 0; nt < 4; ++nt) acc[mt][nt] = zero4();

  bf16x8 bfr[4][2], a01[2][2], a2[6][2];

#define LD_B(b) do { _Pragma("unroll")                                      \
    for (int nt = 0; nt < 4; ++nt) {                                        \
      bfr[nt][0] = *(const bf16x8*)&Bs[b][bh][bro + nt * 1024 + c0];        \
      bfr[nt][1] = *(const bf16x8*)&Bs[b][bh][bro + nt * 1024 + (c0 ^ 32)]; \
    } } while (0)
#define LD_A01(b) do { _Pragma("unroll")                                    \
    for (int mt = 0; mt < 2; ++mt) {                                        \
      a01[mt][0] = *(const bf16x8*)&As[b][wr][aro + mt * 1024 + c0];        \
      a01[mt][1] = *(const bf16x8*)&As[b][wr][aro + mt * 1024 + (c0 ^ 32)]; \
    } } while (0)
#define LD_A2(b) do { _Pragma("unroll")                                     \
    for (int i = 0; i < 6; ++i) {                                           \
      a2[i][0] = *(const bf16x8*)&As[b][wr][aro + (i + 2) * 1024 + c0];     \
      a2[i][1] = *(const bf16x8*)&As[b][wr][aro + (i + 2) * 1024 + (c0^32)];\
    } } while (0)
#define MFMA8(A0, A1, mb) do {                                              \
    __builtin_amdgcn_s_setprio(1);                                          \
    _Pragma("unroll")                                                       \
    for (int nt = 0; nt < 4; ++nt) {                                        \
      acc[(mb)][nt]     = mfma16((A0)[0], bfr[nt][0], acc[(mb)][nt]);       \
      acc[(mb)][nt]     = mfma16((A0)[1], bfr[nt][1], acc[(mb)][nt]);       \
      acc[(mb)+1][nt]   = mfma16((A1)[0], bfr[nt][0], acc[(mb)+1][nt]);     \
      acc[(mb)+1][nt]   = mfma16((A1)[1], bfr[nt][1], acc[(mb)+1][nt]);     \
    }                                                                       \
    __builtin_amdgcn_s_setprio(0);                                          \
  } while (0)

  const int NITER = K >> 7;                     // K/128 (two BK=64 tiles/iter)

  STAGE_A(0, 0); STAGE_A(0, 1); STAGE_B(0, 0); STAGE_B(0, 1);
  STAGE_A(1, 0); STAGE_A(1, 1);
  VMC(4);
  BAR();

  for (int u = 0; u < NITER; ++u) {
    const bool last = (u == NITER - 1);
    const int t1 = 2 * u + 1, t2 = 2 * u + 2, t3 = 2 * u + 3;

    LD_B(0); LD_A01(0);
    STAGE_B(t1, 0);
    BAR(); LGKM0();
    MFMA8(a01[0], a01[1], 0);
    BAR();
    LD_A2(0);
    STAGE_B(t1, 1);
    BAR(); LGKM0();
    MFMA8(a2[0], a2[1], 2);
    BAR();
    if (!last) STAGE_A(t2, 0);
    BAR();
    MFMA8(a2[2], a2[3], 4);
    BAR();
    if (!last) { STAGE_A(t2, 1); VMC(4); } else { VMC(0); }
    BAR();
    MFMA8(a2[4], a2[5], 6);
    BAR();
    LD_B(1); LD_A01(1);
    if (!last) STAGE_B(t2, 0);
    BAR(); LGKM0();
    MFMA8(a01[0], a01[1], 0);
    BAR();
    LD_A2(1);
    if (!last) STAGE_B(t2, 1);
    BAR(); LGKM0();
    MFMA8(a2[0], a2[1], 2);
    BAR();
    if (!last) STAGE_A(t3, 0);
    BAR();
    MFMA8(a2[2], a2[3], 4);
    BAR();
    if (!last) { STAGE_A(t3, 1); VMC(4); }
    BAR();
    MFMA8(a2[4], a2[5], 6);
    BAR();
  }

#pragma unroll
  for (int mt = 0; mt < 8; ++mt)
#pragma unroll
    for (int nt = 0; nt < 4; ++nt)
#pragma unroll
      for (int r = 0; r < 4; ++r) {
        const int row = bm + wr * 128 + mt * 16 + quad * 4 + r;
        const int col = bn + wc * 64 + nt * 16 + l15;
        C[(size_t)row * N + col] = (TC)acc[mt][nt][r];
      }
#undef STAGE_A
#undef STAGE_B
#undef LD_B
#undef LD_A01
#undef LD_A2
#undef MFMA8
}

// ---------- RoPE cos/sin table: tab[s][i] = (cos, sin) ----------
__global__ __launch_bounds__(128)
void rope_table_kernel(const int* __restrict__ pos, float2* __restrict__ tab) {
  const int s = blockIdx.x, i = threadIdx.x;
  const float inv_freq = powf(10000.0f, -(float)i / 128.0f);
  const float ang = (float)pos[s] * inv_freq;
  float sn, cs;
  sincosf(ang, &sn, &cs);
  tab[s * 128 + i] = make_float2(cs, sn);
}

// ---------- RoPE apply, table-driven, bf16x8 vectorized ----------
__global__ __launch_bounds__(256)
void rope_kernel(const float2* __restrict__ tab, bf16_t* __restrict__ qkv) {
  const int bs = blockIdx.x * 16 + (threadIdx.x >> 4);
  const int h  = blockIdx.y;
  const int i0 = (threadIdx.x & 15) * 8;
  const int s  = bs & (SEQ - 1);
  const size_t base = (size_t)bs * QKVN + (size_t)h * HD;
  bf16x8 a = *(const bf16x8*)&qkv[base + i0];
  bf16x8 b = *(const bf16x8*)&qkv[base + 128 + i0];
  bf16x8 oa, ob;
#pragma unroll
  for (int j = 0; j < 8; ++j) {
    const float2 t = tab[s * 128 + i0 + j];
    const float x1 = (float)a[j], x2 = (float)b[j];
    oa[j] = (bf16_t)(x1 * t.x - x2 * t.y);
    ob[j] = (bf16_t)(x2 * t.x + x1 * t.y);
  }
  *(bf16x8*)&qkv[base + i0]       = oa;
  *(bf16x8*)&qkv[base + 128 + i0] = ob;
}

// ---------- V transpose: qkv v-part [s][d] -> Vt[b][d][s] ----------
__global__ __launch_bounds__(256)
void vtrans_kernel(const bf16_t* __restrict__ qkv, bf16_t* __restrict__ Vt) {
  __shared__ __align__(16) bf16_t tile[64][72];
  const int s0 = blockIdx.x * 64, d0 = blockIdx.y * 64, b = blockIdx.z;
  const int t = threadIdx.x, rr = t >> 3, c8 = (t & 7) * 8;
#pragma unroll
  for (int it = 0; it < 2; ++it) {
    const int r = rr + it * 32;
    *(bf16x8*)&tile[r][c8] =
        *(const bf16x8*)&qkv[(size_t)(b * SEQ + s0 + r) * QKVN + 2304 + d0 + c8];
  }
  __syncthreads();
#pragma unroll
  for (int it = 0; it < 2; ++it) {
    const int dd = rr + it * 32;
    bf16x8 o;
#pragma unroll
    for (int j = 0; j < 8; ++j) o[j] = tile[c8 + j][dd];
    *(bf16x8*)&Vt[(size_t)(b * HD + d0 + dd) * SEQ + s0 + c8] = o;
  }
}

// ---------- flash attention: 128-key super-tiles, 2 sub-passes ----------
// TLP avenue is closed (R2/R4-R8: co-residency never happens, reg caps poison
// bigger blocks). Instead shorten the per-tile serial floor: stage 128 keys at
// once (one vmcnt-drain + 3 barriers per 128 keys, vs 2 drains + 4 barriers),
// then process as two 64-key sub-passes so the register working set stays at
// R1's proven ~116 VGPR (sf[4] reused across subs; R2's sf[2][4] spilled).
// P (8 waves x 2KB = 16KB) aliases Ks rows 0..31; alias barrier needed only
// after sub0's QK^T (sub1 reads rows 64..127). Fully-masked second sub-tiles
// are skipped. Grid 256 = 4b x 64 fused complementary q-pairs (qt, 127-qt).
// Block 512 thr = 8 waves = 8 heads. LDS = Ks 64K + Vts 64K = 128 KB.
__global__ __launch_bounds__(512)
void attn_kernel(const bf16_t* __restrict__ qkv, const bf16_t* __restrict__ Vt,
                 bf16_t* __restrict__ O) {
  __shared__ __align__(16) bf16_t Ks[128 * 256];    // [key][d]; rows 0..31 re-used as P
  __shared__ __align__(16) bf16_t Vts[256 * 128];   // [d][key], chunk-swizzled

  const int tid = threadIdx.x, w = tid >> 6, lane = tid & 63;
  const int quad = lane >> 4, l15 = lane & 15;
  const int b = blockIdx.x >> 6;
  const int qtR = blockIdx.x & 63;
  const int h = w;

  bf16_t* PKs = &Ks[w * 1024];                      // per-wave 16x64 P region

  const bf16_t* kbase0 = qkv + (size_t)(b * SEQ) * QKVN + 2048;
  const bf16_t* vbase0 = Vt + (size_t)b * HD * SEQ;

  for (int phase = 0; phase < 2; ++phase) {
    const int qt = phase ? (127 - qtR) : qtR;
    const int q0 = qt * 16;

    // Q fragments (A-layout: m = l15, k = quad*8+j)
    bf16x8 qf[8];
    const bf16_t* qp =
        qkv + (size_t)(b * SEQ + q0 + l15) * QKVN + (size_t)h * HD + quad * 8;
#pragma unroll
    for (int ks = 0; ks < 8; ++ks) qf[ks] = *(const bf16x8*)(qp + ks * 32);

    float mrun[4], lrun[4];
    f32x4 of[16];
#pragma unroll
    for (int r = 0; r < 4; ++r) { mrun[r] = -3e38f; lrun[r] = 0.f; }
#pragma unroll
    for (int dt = 0; dt < 16; ++dt) of[dt] = zero4();

    const int nt128 = q0 / 128 + 1;

    for (int kt = 0; kt < nt128; ++kt) {
      // ---- stage K (128x256) + Vt (256x128): 512 thr, 8 chunks each ----
      const bf16_t* kbase = kbase0 + (size_t)(kt * 128) * QKVN;
      const bf16_t* vbase = vbase0 + kt * 128;
#pragma unroll
      for (int i = 0; i < 8; ++i) {
        const int kr = i * 16 + w * 2 + (lane >> 5);
        const int kc = lane & 31;
        gl2lds16(kbase + (size_t)kr * QKVN + ((kc ^ (kr & 31)) << 3),
                 &Ks[(i * 512 + w * 64) * 8]);
        const int vr = i * 32 + w * 4 + (lane >> 4);
        const int vc = lane & 15;
        gl2lds16(vbase + (size_t)vr * SEQ + ((vc ^ (vr & 15)) << 3),
                 &Vts[(i * 512 + w * 64) * 8]);
      }
      __syncthreads();

#pragma unroll
      for (int sub = 0; sub < 2; ++sub) {
        const int k0g = kt * 128 + sub * 64;
        if (k0g > q0 + 15) break;                 // fully-masked sub-tile (uniform)

        // ---- S = Q K^T (Ks rows sub*64 .. +63) ----
        f32x4 sf[4];
#pragma unroll
        for (int nt = 0; nt < 4; ++nt) {
          f32x4 acc = zero4();
          const int row = sub * 64 + nt * 16 + l15;
#pragma unroll
          for (int ks = 0; ks < 8; ++ks) {
            const int jj = ks * 4 + quad;
            const bf16x8 kf =
                *(const bf16x8*)&Ks[row * 256 + ((jj ^ (row & 31)) << 3)];
            acc = mfma16(qf[ks], kf, acc);
          }
          sf[nt] = acc;
        }

        // ---- scale + causal mask (diag sub-tile only) + row max ----
        const bool needMask = (k0g + 63 > q0);
        float mx[4];
#pragma unroll
        for (int r = 0; r < 4; ++r) {
          const int qg = q0 + quad * 4 + r;
          float v = -3e38f;
#pragma unroll
          for (int nt = 0; nt < 4; ++nt) {
            float s = sf[nt][r] * SCL;
            if (needMask) {
              const int kg = k0g + nt * 16 + l15;
              if (kg > qg) s = -3e38f;
            }
            sf[nt][r] = s;
            v = fmaxf(v, s);
          }
          mx[r] = rmax16(v);
        }

        // ---- defer-max (T13) ----
        float g = 0.f;
#pragma unroll
        for (int r = 0; r < 4; ++r) g = fmaxf(g, mx[r] - mrun[r]);
        const bool resc = !__all(g <= 8.0f);
        f32x4 av;
        if (resc) {
#pragma unroll
          for (int r = 0; r < 4; ++r) {
            const float mn = fmaxf(mrun[r], mx[r]);
            av[r] = __expf(mrun[r] - mn);
            mrun[r] = mn;
            lrun[r] *= av[r];
          }
        }

        if (sub == 0) __syncthreads();   // all waves done with Ks rows 0..63
                                         // before P overwrites rows 0..31.
                                         // sub1 reads rows 64..127: no barrier.

        // ---- P = exp(S - m) into XOR-swizzled P (aliasing Ks), row sums ----
#pragma unroll
        for (int r = 0; r < 4; ++r) {
          const int rowp = quad * 4 + r;
          float sum = 0.f;
#pragma unroll
          for (int nt = 0; nt < 4; ++nt) {
            const float pv = __expf(sf[nt][r] - mrun[r]);
            PKs[rowp * 64 + ((((nt * 2 + (l15 >> 3)) ^ (rowp & 7)) << 3) + (l15 & 7))] =
                (bf16_t)pv;
            sum += pv;
          }
          lrun[r] += rsum16(sum);
        }
        if (resc) {
#pragma unroll
          for (int dt = 0; dt < 16; ++dt) of[dt] *= av;
        }
        __asm__ volatile("s_waitcnt lgkmcnt(0)" ::: "memory");  // wave-local handoff

        // ---- O += P V (Vts key-chunks sub*8 .. +7) ----
        bf16x8 pa[2];
#pragma unroll
        for (int k2 = 0; k2 < 2; ++k2)
          pa[k2] = *(const bf16x8*)&PKs[l15 * 64 + (((k2 * 4 + quad) ^ (l15 & 7)) << 3)];
#pragma unroll
        for (int dt = 0; dt < 16; ++dt) {
          const int row = dt * 16 + l15;
#pragma unroll
          for (int k2 = 0; k2 < 2; ++k2) {
            const int jj = sub * 8 + k2 * 4 + quad;
            const bf16x8 vf =
                *(const bf16x8*)&Vts[row * 128 + ((jj ^ (row & 15)) << 3)];
            of[dt] = mfma16(pa[k2], vf, of[dt]);
          }
        }
      }

      __syncthreads();   // all reads of Ks/P/Vts done before next stage overwrites
    }

    // ---- epilogue: O /= l, store bf16 [b][s][h*HD+d] ----
    f32x4 iv;
#pragma unroll
    for (int r = 0; r < 4; ++r) iv[r] = 1.0f / lrun[r];
#pragma unroll
    for (int dt = 0; dt < 16; ++dt) {
      const f32x4 o = of[dt] * iv;
#pragma unroll
      for (int r = 0; r < 4; ++r)
        O[(size_t)(b * SEQ + q0 + quad * 4 + r) * HID + (size_t)h * HD + dt * 16 + l15] =
            (bf16_t)o[r];
    }
  }
}

// ---------- launch ----------
extern "C" void kernel_launch(void* const* d_in, const int* in_sizes, int n_in,
                              void* d_out, int out_size, void* d_ws, size_t ws_size,
                              hipStream_t stream) {
  const float* hidden  = (const float*)d_in[0];
  const int* positions = (const int*)d_in[1];
  const float* w_qkv   = (const float*)d_in[2];
  const float* w_o     = (const float*)d_in[3];
  float* out           = (float*)d_out;

  char* ws = (char*)d_ws;
  bf16_t* hiddenB = (bf16_t*)ws; ws += (size_t)8192 * 2048 * 2;   // 33.5 MB
  bf16_t* wqkvT   = (bf16_t*)ws; ws += (size_t)2560 * 2048 * 2;   // 10.5 MB
  bf16_t* woT     = (bf16_t*)ws; ws += (size_t)2048 * 2048 * 2;   //  8.4 MB
  bf16_t* qkvB    = (bf16_t*)ws; ws += (size_t)8192 * 2560 * 2;   // 41.9 MB
  bf16_t* VtB     = (bf16_t*)ws; ws += (size_t)4 * 256 * 2048 * 2;//  4.2 MB
  bf16_t* attnB   = (bf16_t*)ws;                                  // 33.5 MB

  // rope table aliases the attnB region (2 MB << 33.5 MB); consumed before
  // attn_kernel writes attnB.
  float2* ropeTab = (float2*)attnB;

  cvt_bf16_kernel<<<8192, 256, 0, stream>>>(hidden, hiddenB);
  transw_kernel<<<dim3(QKVN / 64, HID / 64), 256, 0, stream>>>(w_qkv, wqkvT, HID, QKVN);
  transw_kernel<<<dim3(HID / 64, HID / 64), 256, 0, stream>>>(w_o, woT, HID, HID);
  rope_table_kernel<<<SEQ, 128, 0, stream>>>(positions, ropeTab);

  gemm256_kernel<bf16_t><<<dim3(QKVN / 256, 8192 / 256), 512, 0, stream>>>
      (hiddenB, wqkvT, qkvB, 8192, QKVN, HID);

  rope_kernel<<<dim3(BATCH * SEQ / 16, 9), 256, 0, stream>>>(ropeTab, qkvB);
  vtrans_kernel<<<dim3(SEQ / 64, HD / 64, BATCH), 256, 0, stream>>>(qkvB, VtB);

  attn_kernel<<<256, 512, 0, stream>>>(qkvB, VtB, attnB);

  gemm256_kernel<float><<<dim3(HID / 256, 8192 / 256), 512, 0, stream>>>
      (attnB, woT, out, 8192, HID, HID);
}

// Round 10
// 455.677 us; speedup vs baseline: 2.4237x; 1.0614x over previous
//
#include <hip/hip_runtime.h>
#include <math.h>

constexpr int BATCH = 4;
constexpr int SEQ   = 2048;
constexpr int HID   = 2048;
constexpr int NHEAD = 8;
constexpr int HD    = 256;
constexpr int QKVN  = (NHEAD + 2) * HD;          // 2560
constexpr float SCL = 0.0625f;                   // 256^-0.5

typedef __bf16 bf16_t;
typedef __bf16 bf16x8 __attribute__((ext_vector_type(8)));
typedef float  f32x4  __attribute__((ext_vector_type(4)));

__device__ __forceinline__ f32x4 zero4() {
  f32x4 z; z[0] = 0.f; z[1] = 0.f; z[2] = 0.f; z[3] = 0.f; return z;
}

__device__ __forceinline__ f32x4 mfma16(bf16x8 a, bf16x8 b, f32x4 c) {
  return __builtin_amdgcn_mfma_f32_16x16x32_bf16(a, b, c, 0, 0, 0);
}

// async global->LDS, 16B per lane. lds must be wave-uniform base; HW adds lane*16.
__device__ __forceinline__ void gl2lds16(const void* g, void* lds) {
  typedef __attribute__((address_space(1))) void* gp_t;
  typedef __attribute__((address_space(3))) void* lp_t;
  __builtin_amdgcn_global_load_lds((gp_t)(size_t)g,
                                   (lp_t)(unsigned int)(size_t)lds, 16, 0, 0);
}

__device__ __forceinline__ float rmax16(float v) {
#pragma unroll
  for (int o = 1; o < 16; o <<= 1) v = fmaxf(v, __shfl_xor(v, o));
  return v;
}
__device__ __forceinline__ float rsum16(float v) {
#pragma unroll
  for (int o = 1; o < 16; o <<= 1) v += __shfl_xor(v, o);
  return v;
}

// ---------- fp32 -> bf16 bulk convert (8 elems/thread) ----------
__global__ __launch_bounds__(256)
void cvt_bf16_kernel(const float* __restrict__ in, bf16_t* __restrict__ out) {
  const int i = blockIdx.x * 256 + threadIdx.x;
  const float4 a = ((const float4*)in)[i * 2];
  const float4 b = ((const float4*)in)[i * 2 + 1];
  bf16x8 o;
  o[0] = (bf16_t)a.x; o[1] = (bf16_t)a.y; o[2] = (bf16_t)a.z; o[3] = (bf16_t)a.w;
  o[4] = (bf16_t)b.x; o[5] = (bf16_t)b.y; o[6] = (bf16_t)b.z; o[7] = (bf16_t)b.w;
  ((bf16x8*)out)[i] = o;
}

// ---------- w[K][N] fp32 -> wT[N][K] bf16, 64x64 tiles ----------
__global__ __launch_bounds__(256)
void transw_kernel(const float* __restrict__ w, bf16_t* __restrict__ wT, int K, int N) {
  __shared__ __align__(16) bf16_t tile[64][72];
  const int n0 = blockIdx.x * 64, k0 = blockIdx.y * 64;
  const int t = threadIdx.x, rr = t >> 3, c8 = (t & 7) * 8;
#pragma unroll
  for (int it = 0; it < 2; ++it) {
    const int r = rr + it * 32;
    const float4* p = (const float4*)(w + (size_t)(k0 + r) * N + n0 + c8);
    const float4 a = p[0], b = p[1];
    bf16x8 o;
    o[0] = (bf16_t)a.x; o[1] = (bf16_t)a.y; o[2] = (bf16_t)a.z; o[3] = (bf16_t)a.w;
    o[4] = (bf16_t)b.x; o[5] = (bf16_t)b.y; o[6] = (bf16_t)b.z; o[7] = (bf16_t)b.w;
    *(bf16x8*)&tile[r][c8] = o;
  }
  __syncthreads();
#pragma unroll
  for (int it = 0; it < 2; ++it) {
    const int rn = rr + it * 32;
    bf16x8 o;
#pragma unroll
    for (int j = 0; j < 8; ++j) o[j] = tile[c8 + j][rn];
    *(bf16x8*)&wT[(size_t)(n0 + rn) * K + k0 + c8] = o;
  }
}

// =====================================================================
// 256x256 8-phase GEMM (m201 template, plain HIP): C[M][N] = A * BT^T
// + T1 bijective XCD swizzle (grids 320 and 256, both % 8 == 0)
// =====================================================================
#define BAR()   __builtin_amdgcn_s_barrier()
#define LGKM0() do { asm volatile("s_waitcnt lgkmcnt(0)" ::: "memory"); \
                     __builtin_amdgcn_sched_barrier(0); } while (0)
#define VMC(n)  asm volatile("s_waitcnt vmcnt(" #n ")" ::: "memory")

template <typename TC>
__global__ __launch_bounds__(512)
void gemm256_kernel(const bf16_t* __restrict__ A, const bf16_t* __restrict__ BT,
                    TC* __restrict__ C, int M, int N, int K) {
  __shared__ __align__(16) bf16_t As[2][2][128 * 64];   // [buf][half] 64 KB
  __shared__ __align__(16) bf16_t Bs[2][2][128 * 64];   // 64 KB

  const int tid = threadIdx.x;
  const int w = tid >> 6, lane = tid & 63;
  const int wr = w >> 2, wc = w & 3;
  const int quad = lane >> 4, l15 = lane & 15;

  // T1: XCD-aware bijective remap (nwg % 8 == 0 for both launches)
  const int gx = gridDim.x;
  const int nwg = gx * gridDim.y;
  const int flat = blockIdx.y * gx + blockIdx.x;
  const int cpx = nwg >> 3;
  const int swz = (flat & 7) * cpx + (flat >> 3);
  const int bm = (swz / gx) * 256, bn = (swz % gx) * 256;

  const int srow = tid >> 3;                    // 0..63 row within 64-row chunk
  const int sc16 = (tid & 7) ^ (srow & 7);      // pre-swizzled source chunk
  const bf16_t* Asrc = A  + (size_t)(bm + srow) * K + sc16 * 8;
  const bf16_t* Bsrc = BT + (size_t)(bn + srow) * K + sc16 * 8;

#define STAGE_A(t, h) do {                                                  \
    const bf16_t* _s = Asrc + (size_t)((h) * 128) * K + (t) * 64;           \
    gl2lds16(_s,                 &As[(t) & 1][h][w * 512]);                 \
    gl2lds16(_s + (size_t)64 * K, &As[(t) & 1][h][4096 + w * 512]);         \
  } while (0)
#define STAGE_B(t, h) do {                                                  \
    const bf16_t* _s = Bsrc + (size_t)((h) * 128) * K + (t) * 64;           \
    gl2lds16(_s,                 &Bs[(t) & 1][h][w * 512]);                 \
    gl2lds16(_s + (size_t)64 * K, &Bs[(t) & 1][h][4096 + w * 512]);         \
  } while (0)

  const int c0  = ((quad ^ (l15 & 7)) << 3);
  const int aro = l15 * 64;                     // + mt*1024
  const int bh  = wc >> 1;
  const int bro = ((wc & 1) * 64 + l15) * 64;   // + nt*1024

  f32x4 acc[8][4];
#pragma unroll
  for (int mt = 0; mt < 8; ++mt)
#pragma unroll
    for (int nt = 0; nt < 4; ++nt) acc[mt][nt] = zero4();

  bf16x8 bfr[4][2], a01[2][2], a2[6][2];

#define LD_B(b) do { _Pragma("unroll")                                      \
    for (int nt = 0; nt < 4; ++nt) {                                        \
      bfr[nt][0] = *(const bf16x8*)&Bs[b][bh][bro + nt * 1024 + c0];        \
      bfr[nt][1] = *(const bf16x8*)&Bs[b][bh][bro + nt * 1024 + (c0 ^ 32)]; \
    } } while (0)
#define LD_A01(b) do { _Pragma("unroll")                                    \
    for (int mt = 0; mt < 2; ++mt) {                                        \
      a01[mt][0] = *(const bf16x8*)&As[b][wr][aro + mt * 1024 + c0];        \
      a01[mt][1] = *(const bf16x8*)&As[b][wr][aro + mt * 1024 + (c0 ^ 32)]; \
    } } while (0)
#define LD_A2(b) do { _Pragma("unroll")                                     \
    for (int i = 0; i < 6; ++i) {                                           \
      a2[i][0] = *(const bf16x8*)&As[b][wr][aro + (i + 2) * 1024 + c0];     \
      a2[i][1] = *(const bf16x8*)&As[b][wr][aro + (i + 2) * 1024 + (c0^32)];\
    } } while (0)
#define MFMA8(A0, A1, mb) do {                                              \
    __builtin_amdgcn_s_setprio(1);                                          \
    _Pragma("unroll")                                                       \
    for (int nt = 0; nt < 4; ++nt) {                                        \
      acc[(mb)][nt]     = mfma16((A0)[0], bfr[nt][0], acc[(mb)][nt]);       \
      acc[(mb)][nt]     = mfma16((A0)[1], bfr[nt][1], acc[(mb)][nt]);       \
      acc[(mb)+1][nt]   = mfma16((A1)[0], bfr[nt][0], acc[(mb)+1][nt]);     \
      acc[(mb)+1][nt]   = mfma16((A1)[1], bfr[nt][1], acc[(mb)+1][nt]);     \
    }                                                                       \
    __builtin_amdgcn_s_setprio(0);                                          \
  } while (0)

  const int NITER = K >> 7;                     // K/128 (two BK=64 tiles/iter)

  STAGE_A(0, 0); STAGE_A(0, 1); STAGE_B(0, 0); STAGE_B(0, 1);
  STAGE_A(1, 0); STAGE_A(1, 1);
  VMC(4);
  BAR();

  for (int u = 0; u < NITER; ++u) {
    const bool last = (u == NITER - 1);
    const int t1 = 2 * u + 1, t2 = 2 * u + 2, t3 = 2 * u + 3;

    LD_B(0); LD_A01(0);
    STAGE_B(t1, 0);
    BAR(); LGKM0();
    MFMA8(a01[0], a01[1], 0);
    BAR();
    LD_A2(0);
    STAGE_B(t1, 1);
    BAR(); LGKM0();
    MFMA8(a2[0], a2[1], 2);
    BAR();
    if (!last) STAGE_A(t2, 0);
    BAR();
    MFMA8(a2[2], a2[3], 4);
    BAR();
    if (!last) { STAGE_A(t2, 1); VMC(4); } else { VMC(0); }
    BAR();
    MFMA8(a2[4], a2[5], 6);
    BAR();
    LD_B(1); LD_A01(1);
    if (!last) STAGE_B(t2, 0);
    BAR(); LGKM0();
    MFMA8(a01[0], a01[1], 0);
    BAR();
    LD_A2(1);
    if (!last) STAGE_B(t2, 1);
    BAR(); LGKM0();
    MFMA8(a2[0], a2[1], 2);
    BAR();
    if (!last) STAGE_A(t3, 0);
    BAR();
    MFMA8(a2[2], a2[3], 4);
    BAR();
    if (!last) { STAGE_A(t3, 1); VMC(4); }
    BAR();
    MFMA8(a2[4], a2[5], 6);
    BAR();
  }

#pragma unroll
  for (int mt = 0; mt < 8; ++mt)
#pragma unroll
    for (int nt = 0; nt < 4; ++nt)
#pragma unroll
      for (int r = 0; r < 4; ++r) {
        const int row = bm + wr * 128 + mt * 16 + quad * 4 + r;
        const int col = bn + wc * 64 + nt * 16 + l15;
        C[(size_t)row * N + col] = (TC)acc[mt][nt][r];
      }
#undef STAGE_A
#undef STAGE_B
#undef LD_B
#undef LD_A01
#undef LD_A2
#undef MFMA8
}

// ---------- RoPE cos/sin table: tab[s][i] = (cos, sin) ----------
__global__ __launch_bounds__(128)
void rope_table_kernel(const int* __restrict__ pos, float2* __restrict__ tab) {
  const int s = blockIdx.x, i = threadIdx.x;
  const float inv_freq = powf(10000.0f, -(float)i / 128.0f);
  const float ang = (float)pos[s] * inv_freq;
  float sn, cs;
  sincosf(ang, &sn, &cs);
  tab[s * 128 + i] = make_float2(cs, sn);
}

// ---------- RoPE apply, table-driven, bf16x8 vectorized ----------
__global__ __launch_bounds__(256)
void rope_kernel(const float2* __restrict__ tab, bf16_t* __restrict__ qkv) {
  const int bs = blockIdx.x * 16 + (threadIdx.x >> 4);
  const int h  = blockIdx.y;
  const int i0 = (threadIdx.x & 15) * 8;
  const int s  = bs & (SEQ - 1);
  const size_t base = (size_t)bs * QKVN + (size_t)h * HD;
  bf16x8 a = *(const bf16x8*)&qkv[base + i0];
  bf16x8 b = *(const bf16x8*)&qkv[base + 128 + i0];
  bf16x8 oa, ob;
#pragma unroll
  for (int j = 0; j < 8; ++j) {
    const float2 t = tab[s * 128 + i0 + j];
    const float x1 = (float)a[j], x2 = (float)b[j];
    oa[j] = (bf16_t)(x1 * t.x - x2 * t.y);
    ob[j] = (bf16_t)(x2 * t.x + x1 * t.y);
  }
  *(bf16x8*)&qkv[base + i0]       = oa;
  *(bf16x8*)&qkv[base + 128 + i0] = ob;
}

// ---------- V transpose: qkv v-part [s][d] -> Vt[b][d][s] ----------
__global__ __launch_bounds__(256)
void vtrans_kernel(const bf16_t* __restrict__ qkv, bf16_t* __restrict__ Vt) {
  __shared__ __align__(16) bf16_t tile[64][72];
  const int s0 = blockIdx.x * 64, d0 = blockIdx.y * 64, b = blockIdx.z;
  const int t = threadIdx.x, rr = t >> 3, c8 = (t & 7) * 8;
#pragma unroll
  for (int it = 0; it < 2; ++it) {
    const int r = rr + it * 32;
    *(bf16x8*)&tile[r][c8] =
        *(const bf16x8*)&qkv[(size_t)(b * SEQ + s0 + r) * QKVN + 2304 + d0 + c8];
  }
  __syncthreads();
#pragma unroll
  for (int it = 0; it < 2; ++it) {
    const int dd = rr + it * 32;
    bf16x8 o;
#pragma unroll
    for (int j = 0; j < 8; ++j) o[j] = tile[c8 + j][dd];
    *(bf16x8*)&Vt[(size_t)(b * HD + d0 + dd) * SEQ + s0 + c8] = o;
  }
}

// ---------- flash attention (round-1 config: PROVEN LOCAL OPTIMUM, 139 us) --
// 8 waves = 8 heads share K/V tiles; fused complementary q-pair (qt, 127-qt)
// per block -> uniform ~33 K-tile iterations; 2-phase prefetch (stage kt+1
// into buf^1 while computing kt) -- R9 proved removing this costs ~12 us.
// 9 structural variants (R2,R4-R9) all regressed; do not touch.
__global__ __launch_bounds__(512)
void attn_kernel(const bf16_t* __restrict__ qkv, const bf16_t* __restrict__ Vt,
                 bf16_t* __restrict__ O) {
  __shared__ __align__(16) bf16_t Ks[2][64 * 256];
  __shared__ __align__(16) bf16_t Vts[2][256 * 64];
  __shared__ __align__(16) bf16_t Pl[8][16][72];

  const int tid = threadIdx.x, w = tid >> 6, lane = tid & 63;
  const int quad = lane >> 4, l15 = lane & 15;
  const int b = blockIdx.x >> 6;
  const int qtR = blockIdx.x & 63;
  const int h = w;

  const int krow_base = w * 2 + (lane >> 5);
  const int kcol = lane & 31;
  const int vrow_base = w * 8 + (lane >> 3);
  const int vcol = lane & 7;

  const bf16_t* kbase0 = qkv + (size_t)(b * SEQ) * QKVN + 2048;
  const bf16_t* vbase0 = Vt + (size_t)b * HD * SEQ;

  auto stage = [&](int kt, int buf) {
    const bf16_t* kbase = kbase0 + (size_t)(kt * 64) * QKVN;
#pragma unroll
    for (int i = 0; i < 4; ++i) {
      const int r = i * 16 + krow_base;
      gl2lds16(kbase + (size_t)r * QKVN + ((kcol ^ (r & 31)) << 3),
               &Ks[buf][(i * 512 + w * 64) * 8]);
    }
    const bf16_t* vbase = vbase0 + kt * 64;
#pragma unroll
    for (int i = 0; i < 4; ++i) {
      const int r = i * 64 + vrow_base;
      gl2lds16(vbase + (size_t)r * SEQ + ((vcol ^ (r & 7)) << 3),
               &Vts[buf][(i * 512 + w * 64) * 8]);
    }
  };

  for (int phase = 0; phase < 2; ++phase) {
    const int qt = phase ? (127 - qtR) : qtR;
    const int q0 = qt * 16;

    bf16x8 qf[8];
    const bf16_t* qp =
        qkv + (size_t)(b * SEQ + q0 + l15) * QKVN + (size_t)h * HD + quad * 8;
#pragma unroll
    for (int ks = 0; ks < 8; ++ks) qf[ks] = *(const bf16x8*)(qp + ks * 32);

    float mrun[4], lrun[4];
    f32x4 of[16];
#pragma unroll
    for (int r = 0; r < 4; ++r) { mrun[r] = -3e38f; lrun[r] = 0.f; }
#pragma unroll
    for (int dt = 0; dt < 16; ++dt) of[dt] = zero4();

    const int ntiles = q0 / 64 + 1;
    int cur = 0;
    stage(0, 0);
    __syncthreads();

    for (int kt = 0; kt < ntiles; ++kt) {
      if (kt + 1 < ntiles) stage(kt + 1, cur ^ 1);

      const bf16_t* ksb = Ks[cur];
      const bf16_t* vsb = Vts[cur];

      f32x4 sf[4];
#pragma unroll
      for (int nt = 0; nt < 4; ++nt) {
        f32x4 acc = zero4();
        const int row = nt * 16 + l15;
#pragma unroll
        for (int ks = 0; ks < 8; ++ks) {
          const int j = ks * 4 + quad;
          const bf16x8 kf = *(const bf16x8*)&ksb[row * 256 + ((j ^ (row & 31)) << 3)];
          acc = mfma16(qf[ks], kf, acc);
        }
        sf[nt] = acc;
      }

      const bool lastTile = (kt == ntiles - 1);
      float mx[4];
#pragma unroll
      for (int r = 0; r < 4; ++r) {
        const int qg = q0 + quad * 4 + r;
        float v = -3e38f;
#pragma unroll
        for (int nt = 0; nt < 4; ++nt) {
          float s = sf[nt][r] * SCL;
          if (lastTile) {
            const int kg = kt * 64 + nt * 16 + l15;
            if (kg > qg) s = -3e38f;
          }
          sf[nt][r] = s;
          v = fmaxf(v, s);
        }
        mx[r] = rmax16(v);
      }

      float g = 0.f;
#pragma unroll
      for (int r = 0; r < 4; ++r) g = fmaxf(g, mx[r] - mrun[r]);
      const bool resc = !__all(g <= 8.0f);
      f32x4 av;
      if (resc) {
#pragma unroll
        for (int r = 0; r < 4; ++r) {
          const float mn = fmaxf(mrun[r], mx[r]);
          av[r] = __expf(mrun[r] - mn);
          mrun[r] = mn;
          lrun[r] *= av[r];
        }
      }

#pragma unroll
      for (int r = 0; r < 4; ++r) {
        float sum = 0.f;
#pragma unroll
        for (int nt = 0; nt < 4; ++nt) {
          const float pv = __expf(sf[nt][r] - mrun[r]);
          Pl[w][quad * 4 + r][nt * 16 + l15] = (bf16_t)pv;
          sum += pv;
        }
        lrun[r] += rsum16(sum);
      }
      if (resc) {
#pragma unroll
        for (int dt = 0; dt < 16; ++dt) of[dt] *= av;
      }
      __asm__ volatile("s_waitcnt lgkmcnt(0)" ::: "memory");

      bf16x8 pa[2];
#pragma unroll
      for (int k2 = 0; k2 < 2; ++k2)
        pa[k2] = *(const bf16x8*)&Pl[w][l15][k2 * 32 + quad * 8];
#pragma unroll
      for (int dt = 0; dt < 16; ++dt) {
        const int row = dt * 16 + l15;
#pragma unroll
        for (int k2 = 0; k2 < 2; ++k2) {
          const int j = k2 * 4 + quad;
          const bf16x8 vf = *(const bf16x8*)&vsb[row * 64 + ((j ^ (row & 7)) << 3)];
          of[dt] = mfma16(pa[k2], vf, of[dt]);
        }
      }

      __syncthreads();
      cur ^= 1;
    }

    f32x4 iv;
#pragma unroll
    for (int r = 0; r < 4; ++r) iv[r] = 1.0f / lrun[r];
#pragma unroll
    for (int dt = 0; dt < 16; ++dt) {
      const f32x4 o = of[dt] * iv;
#pragma unroll
      for (int r = 0; r < 4; ++r)
        O[(size_t)(b * SEQ + q0 + quad * 4 + r) * HID + (size_t)h * HD + dt * 16 + l15] =
            (bf16_t)o[r];
    }
  }
}

// ---------- launch ----------
extern "C" void kernel_launch(void* const* d_in, const int* in_sizes, int n_in,
                              void* d_out, int out_size, void* d_ws, size_t ws_size,
                              hipStream_t stream) {
  const float* hidden  = (const float*)d_in[0];
  const int* positions = (const int*)d_in[1];
  const float* w_qkv   = (const float*)d_in[2];
  const float* w_o     = (const float*)d_in[3];
  float* out           = (float*)d_out;

  char* ws = (char*)d_ws;
  bf16_t* hiddenB = (bf16_t*)ws; ws += (size_t)8192 * 2048 * 2;   // 33.5 MB
  bf16_t* wqkvT   = (bf16_t*)ws; ws += (size_t)2560 * 2048 * 2;   // 10.5 MB
  bf16_t* woT     = (bf16_t*)ws; ws += (size_t)2048 * 2048 * 2;   //  8.4 MB
  bf16_t* qkvB    = (bf16_t*)ws; ws += (size_t)8192 * 2560 * 2;   // 41.9 MB
  bf16_t* VtB     = (bf16_t*)ws; ws += (size_t)4 * 256 * 2048 * 2;//  4.2 MB
  bf16_t* attnB   = (bf16_t*)ws;                                  // 33.5 MB

  // rope table aliases the attnB region (2 MB << 33.5 MB); consumed before
  // attn_kernel writes attnB.
  float2* ropeTab = (float2*)attnB;

  cvt_bf16_kernel<<<8192, 256, 0, stream>>>(hidden, hiddenB);
  transw_kernel<<<dim3(QKVN / 64, HID / 64), 256, 0, stream>>>(w_qkv, wqkvT, HID, QKVN);
  transw_kernel<<<dim3(HID / 64, HID / 64), 256, 0, stream>>>(w_o, woT, HID, HID);
  rope_table_kernel<<<SEQ, 128, 0, stream>>>(positions, ropeTab);

  gemm256_kernel<bf16_t><<<dim3(QKVN / 256, 8192 / 256), 512, 0, stream>>>
      (hiddenB, wqkvT, qkvB, 8192, QKVN, HID);

  rope_kernel<<<dim3(BATCH * SEQ / 16, 9), 256, 0, stream>>>(ropeTab, qkvB);
  vtrans_kernel<<<dim3(SEQ / 64, HD / 64, BATCH), 256, 0, stream>>>(qkvB, VtB);

  attn_kernel<<<256, 512, 0, stream>>>(qkvB, VtB, attnB);

  gemm256_kernel<float><<<dim3(HID / 256, 8192 / 256), 512, 0, stream>>>
      (attnB, woT, out, 8192, HID, HID);
}